// Round 2
// baseline (357.458 us; speedup 1.0000x reference)
//
#include <hip/hip_runtime.h>
#include <hip/hip_bf16.h>
#include <math.h>

// Problem constants (match reference)
#define NT_     64000
#define E_      400000
#define B_      128
#define L_      50
#define KD_     256     // K*D
#define D_      64
#define N_USER_ 100000
#define MAXN_   (B_*L_ + B_)   // 6528 max distinct head nodes

// Gumbel bits variant: 1 = partitionable threefry, XOR-fold (modern JAX default)
//                      0 = original split-halves threefry
//                      2 = partitionable, low word only
#define GUMBEL_VARIANT 1

// ---------------- wave helpers ----------------
__device__ __forceinline__ float wred(float v){
#pragma unroll
  for(int s=32;s;s>>=1) v += __shfl_xor(v, s, 64);
  return v;
}
__device__ __forceinline__ int wredi(int v){
#pragma unroll
  for(int s=32;s;s>>=1) v += __shfl_xor(v, s, 64);
  return v;
}

// ---------------- threefry2x32 (JAX key(1) == (0,1)) ----------------
__device__ __forceinline__ unsigned rotl(unsigned x, int r){ return (x<<r)|(x>>(32-r)); }

__device__ void tf2x32(unsigned c0, unsigned c1, unsigned &o0, unsigned &o1){
  const unsigned k0=0u, k1=1u;
  const unsigned k2=k0^k1^0x1BD11BDAu;
  unsigned x0=c0+k0, x1=c1+k1;
  const int RA[4]={13,15,26,6};
  const int RB[4]={17,29,16,24};
#pragma unroll
  for(int i=0;i<4;i++){ x0+=x1; x1=rotl(x1,RA[i]); x1^=x0; }
  x0+=k1; x1+=k2+1u;
#pragma unroll
  for(int i=0;i<4;i++){ x0+=x1; x1=rotl(x1,RB[i]); x1^=x0; }
  x0+=k2; x1+=k0+2u;
#pragma unroll
  for(int i=0;i<4;i++){ x0+=x1; x1=rotl(x1,RA[i]); x1^=x0; }
  x0+=k0; x1+=k1+3u;
#pragma unroll
  for(int i=0;i<4;i++){ x0+=x1; x1=rotl(x1,RB[i]); x1^=x0; }
  x0+=k1; x1+=k2+4u;
#pragma unroll
  for(int i=0;i<4;i++){ x0+=x1; x1=rotl(x1,RA[i]); x1^=x0; }
  x0+=k2; x1+=k0+5u;
  o0=x0; o1=x1;
}

// Gumbel noise matching jax.random.uniform(key(1),(B,L,K),f32,1e-4,1-1e-4)
__device__ float gumbel_at(int idx){
  unsigned bits;
#if GUMBEL_VARIANT == 1
  unsigned o0,o1;
  tf2x32(0u, (unsigned)idx, o0, o1);      // counts uint64 iota: hi=0, lo=idx
  bits = o0 ^ o1;                          // 32-bit fold
#elif GUMBEL_VARIANT == 2
  unsigned o0,o1;
  tf2x32(0u, (unsigned)idx, o0, o1);
  bits = o1;
#else
  const int HALF = (B_*L_*4)/2;            // 12800
  bool lo = idx < HALF;
  unsigned c0 = lo ? (unsigned)idx        : (unsigned)(idx-HALF);
  unsigned c1 = lo ? (unsigned)(idx+HALF) : (unsigned)idx;
  unsigned o0,o1;
  tf2x32(c0,c1,o0,o1);
  bits = lo ? o0 : o1;
#endif
  unsigned fb = (bits>>9) | 0x3f800000u;   // [1,2)
  float f = __uint_as_float(fb) - 1.0f;    // [0,1)
  const float mn=1e-4f, mx=1.0f-1e-4f;
  float u = fmaxf(mn, f*(mx-mn)+mn);
  return -logf(-logf(u));
}

// ---------------- CSR build ----------------
__global__ void count_deg(const int* __restrict__ col, int* __restrict__ cnt){
  int e = blockIdx.x*256 + threadIdx.x;
  if(e<E_) atomicAdd(&cnt[col[e]], 1);
}

__global__ void block_sums(const int* __restrict__ cnt, int* __restrict__ bsum){
  int i = blockIdx.x*256 + threadIdx.x;   // NT_ multiple of 256
  int v = wredi(cnt[i]);
  __shared__ int ws[4];
  if((threadIdx.x&63)==0) ws[threadIdx.x>>6]=v;
  __syncthreads();
  if(threadIdx.x==0) bsum[blockIdx.x]=ws[0]+ws[1]+ws[2]+ws[3];
}

__global__ void scan_bsum(int* __restrict__ bsum){
  const int nb = NT_/256;                 // 250
  int i = threadIdx.x;
  int v = (i<nb)? bsum[i] : 0;
  int lane = i&63, wv = i>>6;
  int s = v;
#pragma unroll
  for(int d=1; d<64; d<<=1){ int t = __shfl_up(s, d, 64); if(lane>=d) s += t; }
  __shared__ int ws[4];
  if(lane==63) ws[wv]=s;
  __syncthreads();
  int add=0;
  for(int w=0;w<wv;w++) add += ws[w];
  if(i<nb) bsum[i] = add + s - v;         // exclusive scan of block sums
}

__global__ void scan_final(const int* __restrict__ cnt, const int* __restrict__ bsumx,
                           int* __restrict__ offs){
  int i = blockIdx.x*256 + threadIdx.x;
  int v = cnt[i];
  int lane = threadIdx.x&63, wv = threadIdx.x>>6;
  int s = v;
#pragma unroll
  for(int d=1; d<64; d<<=1){ int t = __shfl_up(s, d, 64); if(lane>=d) s += t; }
  __shared__ int ws[4];
  if(lane==63) ws[wv]=s;
  __syncthreads();
  int add = bsumx[blockIdx.x];
  for(int w=0;w<wv;w++) add += ws[w];
  offs[i] = add + s - v;
  if(i == NT_-1) offs[NT_] = add + s;     // = E_
}

__global__ void fill_csr(const int* __restrict__ col, const int* __restrict__ offs,
                         int* __restrict__ cur, int* __restrict__ csr){
  int e = blockIdx.x*256 + threadIdx.x;
  if(e<E_){
    int c = col[e];
    int p = atomicAdd(&cur[c], 1);
    csr[offs[c]+p] = e;
  }
}

__global__ void make_dinv(const int* __restrict__ cnt, float* __restrict__ dinv){
  int i = blockIdx.x*256 + threadIdx.x;
  int c = cnt[i];
  dinv[i] = (c>0)? (1.0f/sqrtf((float)c)) : 0.0f;
}

__global__ void make_base(const int* __restrict__ row, const int* __restrict__ col,
                          const float* __restrict__ dinv, float* __restrict__ base){
  int e = blockIdx.x*256 + threadIdx.x;
  if(e<E_) base[e] = dinv[row[e]]*dinv[col[e]];
}

// ---------------- conv1: x1[c] = sum_{e: col=c} embed[node_ids[row]] * base*0.25 ----------------
__global__ void aggregate1(const float* __restrict__ embed, const int* __restrict__ node_ids,
                           const int* __restrict__ row, const int* __restrict__ offs,
                           const int* __restrict__ csr, const float* __restrict__ base,
                           float* __restrict__ x1){
  int c = blockIdx.x, t = threadIdx.x;
  float acc = 0.f;
  int s = offs[c], e = offs[c+1];
  for(int i=s;i<e;i++){
    int eid = csr[i];
    int nid = node_ids[row[eid]];
    acc = fmaf(embed[(size_t)nid*KD_ + t], base[eid]*0.25f, acc);
  }
  x1[(size_t)c*KD_ + t] = acc;
}

// ---------------- mark & dedup head nodes (seq_map ∪ tar_map) ----------------
__global__ void mark_assign(const int* __restrict__ seq_map, const int* __restrict__ tar_map,
                            int* __restrict__ markpos, int* __restrict__ nlist,
                            int* __restrict__ ncount){
  int p = blockIdx.x*256 + threadIdx.x;
  if(p >= MAXN_) return;
  int n = (p < B_*L_) ? seq_map[p] : tar_map[p - B_*L_];
  int old = atomicCAS(&markpos[n], -1, -2);
  if(old == -1){
    int s = atomicAdd(ncount, 1);
    nlist[s] = n;
    __threadfence();
    markpos[n] = s;
  }
}

// ---------------- conv2 fused (only for needed nodes): z -> softmax -> aggregate ----------------
__global__ void conv2_fused(const float* __restrict__ x1, const int* __restrict__ row,
                            const int* __restrict__ offs, const int* __restrict__ csr,
                            const float* __restrict__ base, const int* __restrict__ nlist,
                            const int* __restrict__ ncount, float* __restrict__ x2c){
  int slot = blockIdx.x;
  if(slot >= *ncount) return;
  int c = nlist[slot];
  int t = threadIdx.x, k = t>>6, lane = t&63;
  float tx = tanhf(x1[(size_t)c*KD_ + t]);
  float acc = 0.f;
  __shared__ float zs[4];
  int s = offs[c], e = offs[c+1];
  for(int i=s;i<e;i++){
    int eid = csr[i];
    int r = row[eid];
    float xr = x1[(size_t)r*KD_ + t];
    float zk = wred(xr*tx);               // z[e,k] = dot(x1[row,k,:], tanh(x1[col,k,:]))
    if(lane==0) zs[k] = zk;
    __syncthreads();
    float z0=zs[0], z1=zs[1], z2=zs[2], z3=zs[3];
    // softmax(1+z) over k == softmax(z) (shift-invariant)
    float m = fmaxf(fmaxf(z0,z1), fmaxf(z2,z3));
    float e0=expf(z0-m), e1=expf(z1-m), e2=expf(z2-m), e3=expf(z3-m);
    float inv = base[eid]/(e0+e1+e2+e3);
    float w = ((k==0)?e0:(k==1)?e1:(k==2)?e2:e3) * inv;
    acc = fmaf(xr, w, acc);
    __syncthreads();
  }
  x2c[(size_t)slot*KD_ + t] = acc;
}

// ---------------- head ----------------
__global__ void prep_av(const float* __restrict__ embed, const float* __restrict__ x2c,
                        const int* __restrict__ markpos, const float* __restrict__ W2,
                        const int* __restrict__ uid, const int* __restrict__ sid,
                        const int* __restrict__ tar_map,
                        float* __restrict__ a_v, float* __restrict__ mu,
                        float* __restrict__ inav, float* __restrict__ inau){
  int b = blockIdx.x;
  int t = threadIdx.x;
  int k = t>>6, lane = t&63;
  float xv = x2c[(size_t)markpos[tar_map[b]]*KD_ + t];
  float av = embed[((size_t)(N_USER_ + sid[b]))*KD_ + t];
  const float* wrow = W2 + lane*64;   // a_v[...,e] = sum_d x[...,d]*W2[e,d]
#pragma unroll 8
  for(int d=0; d<64; d++) av = fmaf(__shfl(xv, d, 64), wrow[d], av);
  float au = embed[(size_t)uid[b]*KD_ + t];
  float dot = wred(av*au);
  float nv  = wred(av*av);
  float nu  = wred(au*au);
  a_v[(size_t)b*KD_ + t] = av;
  if(lane==0){
    float rnv = fmaxf(sqrtf(nv), 1e-8f);
    float rnu = fmaxf(sqrtf(nu), 1e-8f);
    mu[b*4+k]   = dot/(rnv*rnu);
    inav[b*4+k] = 1.f/rnv;
    inau[b*4+k] = 1.f/rnu;
  }
}

__global__ void seq_inc(const float* __restrict__ embed, const float* __restrict__ x2c,
                        const int* __restrict__ markpos, const float* __restrict__ W1,
                        const float* __restrict__ a_v,
                        const float* __restrict__ inav, const float* __restrict__ inau,
                        const int* __restrict__ node_ids, const int* __restrict__ seq_map,
                        const int* __restrict__ seq_idx, const int* __restrict__ seq_len,
                        const int* __restrict__ uid,
                        const float* __restrict__ seqs_time, const float* __restrict__ clk_time,
                        const float* __restrict__ tau_p, const float* __restrict__ delta,
                        float* __restrict__ acc){
  int bl = blockIdx.x;
  int b = bl / L_, l = bl % L_;
  if(l >= seq_len[b]) return;           // masked position contributes exactly 0
  int t = threadIdx.x, k = t>>6, lane = t&63;
  int n = seq_map[bl];
  int nid = node_ids[n];
  float xv = x2c[(size_t)markpos[n]*KD_ + t];
  float se = embed[(size_t)nid*KD_ + t];         // resi
  const float* wrow = W1 + lane*64;
#pragma unroll 8
  for(int d=0; d<64; d++) se = fmaf(__shfl(xv, d, 64), wrow[d], se);
  float av = a_v[(size_t)b*KD_ + t];
  float au = embed[(size_t)uid[b]*KD_ + t];
  float dv = wred(se*av);
  float du = wred(se*au);
  float ns = wred(se*se);
  __shared__ float sdv[4], sdu[4], sns[4];
  if(lane==0){ sdv[k]=dv; sdu[k]=du; sns[k]=ns; }
  __syncthreads();
  if(t==0){
    float jv  = expf(-(clk_time[b]-seqs_time[bl]) * (1.0f/1000.0f) * delta[uid[b]]);
    float tau = tau_p[seq_idx[bl]];
    float gam[4], lg[4];
    float m = -1e30f;
#pragma unroll
    for(int kk=0;kk<4;kk++){
      float ins = 1.f/fmaxf(sqrtf(sns[kk]), 1e-8f);
      gam[kk] = sdv[kk]*ins*inav[b*4+kk];
      float logit = sdu[kk]*ins*inau[b*4+kk];
      lg[kk] = (logit + gumbel_at(bl*4+kk))/tau;
      m = fmaxf(m, lg[kk]);
    }
    float es[4], ssum=0.f;
#pragma unroll
    for(int kk=0;kk<4;kk++){ es[kk]=expf(lg[kk]-m); ssum+=es[kk]; }
    float isum = 1.f/ssum;
#pragma unroll
    for(int kk=0;kk<4;kk++)
      atomicAdd(&acc[b*4+kk], jv * gam[kk] * es[kk]*isum);
  }
}

__global__ void finalize(const float* __restrict__ mu, const float* __restrict__ acc,
                         float* __restrict__ out){
  int b = threadIdx.x;
  if(b < B_){
    float s = 0.f;
#pragma unroll
    for(int k=0;k<4;k++) s += mu[b*4+k] + acc[b*4+k];
    out[b] = s * 0.25f;
  }
}

// ---------------- launch ----------------
extern "C" void kernel_launch(void* const* d_in, const int* in_sizes, int n_in,
                              void* d_out, int out_size, void* d_ws, size_t ws_size,
                              hipStream_t stream){
  const float* embed = (const float*)d_in[0];
  const float* delta = (const float*)d_in[1];
  const float* tau_p = (const float*)d_in[2];
  const float* W1    = (const float*)d_in[3];
  const float* W2    = (const float*)d_in[4];
  const float* seqs_time = (const float*)d_in[5];
  const float* clk_time  = (const float*)d_in[6];
  const int* uid      = (const int*)d_in[7];
  const int* sid      = (const int*)d_in[8];
  const int* node_ids = (const int*)d_in[9];
  const int* edge_index = (const int*)d_in[10];
  const int* seq_map  = (const int*)d_in[11];
  const int* tar_map  = (const int*)d_in[12];
  const int* seq_idx  = (const int*)d_in[13];
  const int* seq_len  = (const int*)d_in[14];
  const int* row = edge_index;
  const int* col = edge_index + E_;
  float* out = (float*)d_out;

  // carve: small, head-critical buffers FIRST; big buffers last. Total ~77 MB.
  char* wp = (char*)d_ws;
  size_t o = 0;
  auto carve = [&](size_t bytes)->char*{ char* r = wp + o; o = (o + bytes + 255) & ~(size_t)255; return r; };
  float* mu     = (float*)carve((size_t)B_*4*4);
  float* inav   = (float*)carve((size_t)B_*4*4);
  float* inau   = (float*)carve((size_t)B_*4*4);
  float* acc    = (float*)carve((size_t)B_*4*4);
  int*   bsum   = (int*)  carve((size_t)256*4);
  int*   ncount = (int*)  carve((size_t)4);
  float* a_v    = (float*)carve((size_t)B_*KD_*4);
  int*   nlist  = (int*)  carve((size_t)MAXN_*4);
  float* dinv   = (float*)carve((size_t)NT_*4);
  int*   cnt    = (int*)  carve((size_t)NT_*4);
  int*   cur    = (int*)  carve((size_t)NT_*4);
  int*   offs   = (int*)  carve((size_t)(NT_+1)*4);
  int*   markpos= (int*)  carve((size_t)NT_*4);
  float* base   = (float*)carve((size_t)E_*4);
  int*   csr    = (int*)  carve((size_t)E_*4);
  float* x2c    = (float*)carve((size_t)MAXN_*KD_*4);
  float* x1     = (float*)carve((size_t)NT_*KD_*4);

  hipMemsetAsync(cnt, 0, (size_t)NT_*4, stream);
  hipMemsetAsync(cur, 0, (size_t)NT_*4, stream);
  hipMemsetAsync(markpos, 0xFF, (size_t)NT_*4, stream);   // -1
  hipMemsetAsync(ncount, 0, 4, stream);
  hipMemsetAsync(acc, 0, (size_t)B_*4*4, stream);

  // CSR by col + degree normalization
  count_deg<<<(E_+255)/256, 256, 0, stream>>>(col, cnt);
  block_sums<<<NT_/256, 256, 0, stream>>>(cnt, bsum);
  scan_bsum<<<1, 256, 0, stream>>>(bsum);
  scan_final<<<NT_/256, 256, 0, stream>>>(cnt, bsum, offs);
  fill_csr<<<(E_+255)/256, 256, 0, stream>>>(col, offs, cur, csr);
  make_dinv<<<NT_/256, 256, 0, stream>>>(cnt, dinv);
  make_base<<<(E_+255)/256, 256, 0, stream>>>(row, col, dinv, base);

  // conv1 (full graph; s_q(ones) == 0.25 exactly)
  aggregate1<<<NT_, 256, 0, stream>>>(embed, node_ids, row, offs, csr, base, x1);

  // conv2 only for nodes the head reads (seq_map ∪ tar_map)
  mark_assign<<<(MAXN_+255)/256, 256, 0, stream>>>(seq_map, tar_map, markpos, nlist, ncount);
  conv2_fused<<<MAXN_, 256, 0, stream>>>(x1, row, offs, csr, base, nlist, ncount, x2c);

  // scoring head
  prep_av<<<B_, 256, 0, stream>>>(embed, x2c, markpos, W2, uid, sid, tar_map, a_v, mu, inav, inau);
  seq_inc<<<B_*L_, 256, 0, stream>>>(embed, x2c, markpos, W1, a_v, inav, inau,
                                     node_ids, seq_map, seq_idx, seq_len, uid,
                                     seqs_time, clk_time, tau_p, delta, acc);
  finalize<<<1, 128, 0, stream>>>(mu, acc, out);
}

// Round 3
// 242.213 us; speedup vs baseline: 1.4758x; 1.4758x over previous
//
#include <hip/hip_runtime.h>
#include <hip/hip_bf16.h>
#include <math.h>

// Problem constants (match reference)
#define NT_     64000
#define E_      400000
#define B_      128
#define L_      50
#define KD_     256     // K*D
#define D_      64
#define N_USER_ 100000
#define MAXN_   (B_*L_ + B_)   // 6528 max distinct head nodes

// ---------------- wave helpers ----------------
__device__ __forceinline__ float wred(float v){
#pragma unroll
  for(int s=32;s;s>>=1) v += __shfl_xor(v, s, 64);
  return v;
}
__device__ __forceinline__ int wredi(int v){
#pragma unroll
  for(int s=32;s;s>>=1) v += __shfl_xor(v, s, 64);
  return v;
}

// ---------------- threefry2x32 (JAX key(1) == (0,1)), partitionable XOR-fold ----------------
__device__ __forceinline__ unsigned rotl(unsigned x, int r){ return (x<<r)|(x>>(32-r)); }

__device__ void tf2x32(unsigned c0, unsigned c1, unsigned &o0, unsigned &o1){
  const unsigned k0=0u, k1=1u;
  const unsigned k2=k0^k1^0x1BD11BDAu;
  unsigned x0=c0+k0, x1=c1+k1;
  const int RA[4]={13,15,26,6};
  const int RB[4]={17,29,16,24};
#pragma unroll
  for(int i=0;i<4;i++){ x0+=x1; x1=rotl(x1,RA[i]); x1^=x0; }
  x0+=k1; x1+=k2+1u;
#pragma unroll
  for(int i=0;i<4;i++){ x0+=x1; x1=rotl(x1,RB[i]); x1^=x0; }
  x0+=k2; x1+=k0+2u;
#pragma unroll
  for(int i=0;i<4;i++){ x0+=x1; x1=rotl(x1,RA[i]); x1^=x0; }
  x0+=k0; x1+=k1+3u;
#pragma unroll
  for(int i=0;i<4;i++){ x0+=x1; x1=rotl(x1,RB[i]); x1^=x0; }
  x0+=k1; x1+=k2+4u;
#pragma unroll
  for(int i=0;i<4;i++){ x0+=x1; x1=rotl(x1,RA[i]); x1^=x0; }
  x0+=k2; x1+=k0+5u;
  o0=x0; o1=x1;
}

// Gumbel noise matching jax.random.uniform(key(1),(B,L,K),f32,1e-4,1-1e-4)
__device__ float gumbel_at(int idx){
  unsigned o0,o1;
  tf2x32(0u, (unsigned)idx, o0, o1);      // counts uint64 iota: hi=0, lo=idx
  unsigned bits = o0 ^ o1;                 // 32-bit XOR fold (partitionable)
  unsigned fb = (bits>>9) | 0x3f800000u;   // [1,2)
  float f = __uint_as_float(fb) - 1.0f;    // [0,1)
  const float mn=1e-4f, mx=1.0f-1e-4f;
  float u = fmaxf(mn, f*(mx-mn)+mn);
  return -logf(-logf(u));
}

// ---------------- x0 staging: x0 = embed[node_ids] ----------------
__global__ void gather_x0(const float4* __restrict__ embed4, const int* __restrict__ node_ids,
                          float4* __restrict__ x04){
  int i = blockIdx.x*256 + threadIdx.x;   // over NT_*64 float4s
  int node = i>>6, q = i&63;
  int nid = node_ids[node];
  x04[i] = embed4[(size_t)nid*64 + q];
}

// ---------------- CSR build ----------------
__global__ void count_deg(const int* __restrict__ col, int* __restrict__ cnt){
  int e = blockIdx.x*256 + threadIdx.x;
  if(e<E_) atomicAdd(&cnt[col[e]], 1);
}

__global__ void block_sums(const int* __restrict__ cnt, int* __restrict__ bsum){
  int i = blockIdx.x*256 + threadIdx.x;   // NT_ multiple of 256
  int v = wredi(cnt[i]);
  __shared__ int ws[4];
  if((threadIdx.x&63)==0) ws[threadIdx.x>>6]=v;
  __syncthreads();
  if(threadIdx.x==0) bsum[blockIdx.x]=ws[0]+ws[1]+ws[2]+ws[3];
}

__global__ void scan_bsum(int* __restrict__ bsum){
  const int nb = NT_/256;                 // 250
  int i = threadIdx.x;
  int v = (i<nb)? bsum[i] : 0;
  int lane = i&63, wv = i>>6;
  int s = v;
#pragma unroll
  for(int d=1; d<64; d<<=1){ int t = __shfl_up(s, d, 64); if(lane>=d) s += t; }
  __shared__ int ws[4];
  if(lane==63) ws[wv]=s;
  __syncthreads();
  int add=0;
  for(int w=0;w<wv;w++) add += ws[w];
  if(i<nb) bsum[i] = add + s - v;         // exclusive scan of block sums
}

__global__ void scan_final(const int* __restrict__ cnt, const int* __restrict__ bsumx,
                           int* __restrict__ offs){
  int i = blockIdx.x*256 + threadIdx.x;
  int v = cnt[i];
  int lane = threadIdx.x&63, wv = threadIdx.x>>6;
  int s = v;
#pragma unroll
  for(int d=1; d<64; d<<=1){ int t = __shfl_up(s, d, 64); if(lane>=d) s += t; }
  __shared__ int ws[4];
  if(lane==63) ws[wv]=s;
  __syncthreads();
  int add = bsumx[blockIdx.x];
  for(int w=0;w<wv;w++) add += ws[w];
  offs[i] = add + s - v;
  if(i == NT_-1) offs[NT_] = add + s;     // = E_
}

__global__ void make_dinv(const int* __restrict__ cnt, float* __restrict__ dinv){
  int i = blockIdx.x*256 + threadIdx.x;
  int c = cnt[i];
  dinv[i] = (c>0)? (1.0f/sqrtf((float)c)) : 0.0f;
}

// writes per-slot (src_row, weight = dinv[r]*dinv[c]*0.25) — no edge ids needed downstream
__global__ void fill_csr(const int* __restrict__ row, const int* __restrict__ col,
                         const float* __restrict__ dinv, const int* __restrict__ offs,
                         int* __restrict__ cur, int* __restrict__ src, float* __restrict__ wgt){
  int e = blockIdx.x*256 + threadIdx.x;
  if(e<E_){
    int c = col[e], r = row[e];
    int p = atomicAdd(&cur[c], 1);
    int slot = offs[c]+p;
    src[slot] = r;
    wgt[slot] = dinv[r]*dinv[c]*0.25f;
  }
}

// ---------------- conv1: wave-per-node, float4 per lane, 4-edge unroll ----------------
__global__ void aggregate1(const float4* __restrict__ x04, const int* __restrict__ offs,
                           const int* __restrict__ src, const float* __restrict__ wgt,
                           float4* __restrict__ x14){
  int wv = threadIdx.x>>6, lane = threadIdx.x&63;
  int c = blockIdx.x*4 + wv;
  float4 acc = {0.f,0.f,0.f,0.f};
  int s = offs[c], e = offs[c+1];
  int i = s;
  for(; i+4<=e; i+=4){
    int   s0=src[i],   s1=src[i+1], s2=src[i+2], s3=src[i+3];
    float w0=wgt[i],   w1=wgt[i+1], w2=wgt[i+2], w3=wgt[i+3];
    float4 v0=x04[(size_t)s0*64+lane];
    float4 v1=x04[(size_t)s1*64+lane];
    float4 v2=x04[(size_t)s2*64+lane];
    float4 v3=x04[(size_t)s3*64+lane];
    acc.x = fmaf(v0.x,w0,fmaf(v1.x,w1,fmaf(v2.x,w2,fmaf(v3.x,w3,acc.x))));
    acc.y = fmaf(v0.y,w0,fmaf(v1.y,w1,fmaf(v2.y,w2,fmaf(v3.y,w3,acc.y))));
    acc.z = fmaf(v0.z,w0,fmaf(v1.z,w1,fmaf(v2.z,w2,fmaf(v3.z,w3,acc.z))));
    acc.w = fmaf(v0.w,w0,fmaf(v1.w,w1,fmaf(v2.w,w2,fmaf(v3.w,w3,acc.w))));
  }
  for(; i<e; i++){
    int s0=src[i]; float w0=wgt[i];
    float4 v0=x04[(size_t)s0*64+lane];
    acc.x=fmaf(v0.x,w0,acc.x); acc.y=fmaf(v0.y,w0,acc.y);
    acc.z=fmaf(v0.z,w0,acc.z); acc.w=fmaf(v0.w,w0,acc.w);
  }
  x14[(size_t)c*64+lane] = acc;
}

// ---------------- mark & dedup head nodes (seq_map ∪ tar_map) ----------------
__global__ void mark_assign(const int* __restrict__ seq_map, const int* __restrict__ tar_map,
                            int* __restrict__ markpos, int* __restrict__ nlist,
                            int* __restrict__ ncount){
  int p = blockIdx.x*256 + threadIdx.x;
  if(p >= MAXN_) return;
  int n = (p < B_*L_) ? seq_map[p] : tar_map[p - B_*L_];
  int old = atomicCAS(&markpos[n], -1, -2);
  if(old == -1){
    int s = atomicAdd(ncount, 1);
    nlist[s] = n;
    __threadfence();
    markpos[n] = s;
  }
}

// ---------------- conv2 fused (only head nodes): z -> softmax -> aggregate ----------------
__global__ void conv2_fused(const float* __restrict__ x1, const int* __restrict__ offs,
                            const int* __restrict__ src, const float* __restrict__ wgt,
                            const int* __restrict__ nlist, const int* __restrict__ ncount,
                            float* __restrict__ x2c){
  int slot = blockIdx.x;
  if(slot >= *ncount) return;
  int c = nlist[slot];
  int t = threadIdx.x, k = t>>6, lane = t&63;
  float tx = tanhf(x1[(size_t)c*KD_ + t]);
  float acc = 0.f;
  __shared__ float zs[4];
  int s = offs[c], e = offs[c+1];
  for(int i=s;i<e;i++){
    int r = src[i];
    float xr = x1[(size_t)r*KD_ + t];
    float zk = wred(xr*tx);               // z[e,k] = dot(x1[row,k,:], tanh(x1[col,k,:]))
    if(lane==0) zs[k] = zk;
    __syncthreads();
    float z0=zs[0], z1=zs[1], z2=zs[2], z3=zs[3];
    // softmax(1+z) over k == softmax(z) (shift-invariant)
    float m = fmaxf(fmaxf(z0,z1), fmaxf(z2,z3));
    float e0=expf(z0-m), e1=expf(z1-m), e2=expf(z2-m), e3=expf(z3-m);
    float inv = (4.f*wgt[i])/(e0+e1+e2+e3);   // base = 4*wgt
    float w = ((k==0)?e0:(k==1)?e1:(k==2)?e2:e3) * inv;
    acc = fmaf(xr, w, acc);
    __syncthreads();
  }
  x2c[(size_t)slot*KD_ + t] = acc;
}

// ---------------- head ----------------
__global__ void prep_av(const float* __restrict__ embed, const float* __restrict__ x2c,
                        const int* __restrict__ markpos, const float* __restrict__ W2,
                        const int* __restrict__ uid, const int* __restrict__ sid,
                        const int* __restrict__ tar_map,
                        float* __restrict__ a_v, float* __restrict__ mu,
                        float* __restrict__ inav, float* __restrict__ inau){
  int b = blockIdx.x;
  int t = threadIdx.x;
  int k = t>>6, lane = t&63;
  float xv = x2c[(size_t)markpos[tar_map[b]]*KD_ + t];
  float av = embed[((size_t)(N_USER_ + sid[b]))*KD_ + t];
  const float* wrow = W2 + lane*64;   // a_v[...,e] = sum_d x[...,d]*W2[e,d]
#pragma unroll 8
  for(int d=0; d<64; d++) av = fmaf(__shfl(xv, d, 64), wrow[d], av);
  float au = embed[(size_t)uid[b]*KD_ + t];
  float dot = wred(av*au);
  float nv  = wred(av*av);
  float nu  = wred(au*au);
  a_v[(size_t)b*KD_ + t] = av;
  if(lane==0){
    float rnv = fmaxf(sqrtf(nv), 1e-8f);
    float rnu = fmaxf(sqrtf(nu), 1e-8f);
    mu[b*4+k]   = dot/(rnv*rnu);
    inav[b*4+k] = 1.f/rnv;
    inau[b*4+k] = 1.f/rnu;
  }
}

__global__ void seq_inc(const float* __restrict__ embed, const float* __restrict__ x2c,
                        const int* __restrict__ markpos, const float* __restrict__ W1,
                        const float* __restrict__ a_v,
                        const float* __restrict__ inav, const float* __restrict__ inau,
                        const int* __restrict__ node_ids, const int* __restrict__ seq_map,
                        const int* __restrict__ seq_idx, const int* __restrict__ seq_len,
                        const int* __restrict__ uid,
                        const float* __restrict__ seqs_time, const float* __restrict__ clk_time,
                        const float* __restrict__ tau_p, const float* __restrict__ delta,
                        float* __restrict__ acc){
  int bl = blockIdx.x;
  int b = bl / L_, l = bl % L_;
  if(l >= seq_len[b]) return;           // masked position contributes exactly 0
  int t = threadIdx.x, k = t>>6, lane = t&63;
  int n = seq_map[bl];
  int nid = node_ids[n];
  float xv = x2c[(size_t)markpos[n]*KD_ + t];
  float se = embed[(size_t)nid*KD_ + t];         // resi
  const float* wrow = W1 + lane*64;
#pragma unroll 8
  for(int d=0; d<64; d++) se = fmaf(__shfl(xv, d, 64), wrow[d], se);
  float av = a_v[(size_t)b*KD_ + t];
  float au = embed[(size_t)uid[b]*KD_ + t];
  float dv = wred(se*av);
  float du = wred(se*au);
  float ns = wred(se*se);
  __shared__ float sdv[4], sdu[4], sns[4];
  if(lane==0){ sdv[k]=dv; sdu[k]=du; sns[k]=ns; }
  __syncthreads();
  if(t==0){
    float jv  = expf(-(clk_time[b]-seqs_time[bl]) * (1.0f/1000.0f) * delta[uid[b]]);
    float tau = tau_p[seq_idx[bl]];
    float gam[4], lg[4];
    float m = -1e30f;
#pragma unroll
    for(int kk=0;kk<4;kk++){
      float ins = 1.f/fmaxf(sqrtf(sns[kk]), 1e-8f);
      gam[kk] = sdv[kk]*ins*inav[b*4+kk];
      float logit = sdu[kk]*ins*inau[b*4+kk];
      lg[kk] = (logit + gumbel_at(bl*4+kk))/tau;
      m = fmaxf(m, lg[kk]);
    }
    float es[4], ssum=0.f;
#pragma unroll
    for(int kk=0;kk<4;kk++){ es[kk]=expf(lg[kk]-m); ssum+=es[kk]; }
    float isum = 1.f/ssum;
#pragma unroll
    for(int kk=0;kk<4;kk++)
      atomicAdd(&acc[b*4+kk], jv * gam[kk] * es[kk]*isum);
  }
}

__global__ void finalize(const float* __restrict__ mu, const float* __restrict__ acc,
                         float* __restrict__ out){
  int b = threadIdx.x;
  if(b < B_){
    float s = 0.f;
#pragma unroll
    for(int k=0;k<4;k++) s += mu[b*4+k] + acc[b*4+k];
    out[b] = s * 0.25f;
  }
}

// ---------------- launch ----------------
extern "C" void kernel_launch(void* const* d_in, const int* in_sizes, int n_in,
                              void* d_out, int out_size, void* d_ws, size_t ws_size,
                              hipStream_t stream){
  const float* embed = (const float*)d_in[0];
  const float* delta = (const float*)d_in[1];
  const float* tau_p = (const float*)d_in[2];
  const float* W1    = (const float*)d_in[3];
  const float* W2    = (const float*)d_in[4];
  const float* seqs_time = (const float*)d_in[5];
  const float* clk_time  = (const float*)d_in[6];
  const int* uid      = (const int*)d_in[7];
  const int* sid      = (const int*)d_in[8];
  const int* node_ids = (const int*)d_in[9];
  const int* edge_index = (const int*)d_in[10];
  const int* seq_map  = (const int*)d_in[11];
  const int* tar_map  = (const int*)d_in[12];
  const int* seq_idx  = (const int*)d_in[13];
  const int* seq_len  = (const int*)d_in[14];
  const int* row = edge_index;
  const int* col = edge_index + E_;
  float* out = (float*)d_out;

  // carve: small, head-critical buffers FIRST; big buffers last. Total ~139 MB.
  char* wp = (char*)d_ws;
  size_t o = 0;
  auto carve = [&](size_t bytes)->char*{ char* r = wp + o; o = (o + bytes + 255) & ~(size_t)255; return r; };
  float* mu     = (float*)carve((size_t)B_*4*4);
  float* inav   = (float*)carve((size_t)B_*4*4);
  float* inau   = (float*)carve((size_t)B_*4*4);
  float* acc    = (float*)carve((size_t)B_*4*4);
  int*   bsum   = (int*)  carve((size_t)256*4);
  int*   ncount = (int*)  carve((size_t)4);
  float* a_v    = (float*)carve((size_t)B_*KD_*4);
  int*   nlist  = (int*)  carve((size_t)MAXN_*4);
  float* dinv   = (float*)carve((size_t)NT_*4);
  int*   cnt    = (int*)  carve((size_t)NT_*4);
  int*   cur    = (int*)  carve((size_t)NT_*4);
  int*   offs   = (int*)  carve((size_t)(NT_+1)*4);
  int*   markpos= (int*)  carve((size_t)NT_*4);
  int*   src    = (int*)  carve((size_t)E_*4);
  float* wgt    = (float*)carve((size_t)E_*4);
  float* x2c    = (float*)carve((size_t)MAXN_*KD_*4);
  float* x0     = (float*)carve((size_t)NT_*KD_*4);   // 64 MB
  float* x1     = (float*)carve((size_t)NT_*KD_*4);   // 64 MB

  hipMemsetAsync(cnt, 0, (size_t)NT_*4, stream);
  hipMemsetAsync(cur, 0, (size_t)NT_*4, stream);
  hipMemsetAsync(markpos, 0xFF, (size_t)NT_*4, stream);   // -1
  hipMemsetAsync(ncount, 0, 4, stream);
  hipMemsetAsync(acc, 0, (size_t)B_*4*4, stream);

  // x0 = embed[node_ids] (64 MB, L3-resident for the aggregate)
  gather_x0<<<NT_*64/256, 256, 0, stream>>>((const float4*)embed, node_ids, (float4*)x0);

  // CSR by col with fused (src,weight) records
  count_deg<<<(E_+255)/256, 256, 0, stream>>>(col, cnt);
  block_sums<<<NT_/256, 256, 0, stream>>>(cnt, bsum);
  scan_bsum<<<1, 256, 0, stream>>>(bsum);
  scan_final<<<NT_/256, 256, 0, stream>>>(cnt, bsum, offs);
  make_dinv<<<NT_/256, 256, 0, stream>>>(cnt, dinv);
  fill_csr<<<(E_+255)/256, 256, 0, stream>>>(row, col, dinv, offs, cur, src, wgt);

  // conv1 (full graph; s_q(ones) == 0.25 folded into wgt)
  aggregate1<<<NT_/4, 256, 0, stream>>>((const float4*)x0, offs, src, wgt, (float4*)x1);

  // conv2 only for nodes the head reads (seq_map ∪ tar_map)
  mark_assign<<<(MAXN_+255)/256, 256, 0, stream>>>(seq_map, tar_map, markpos, nlist, ncount);
  conv2_fused<<<MAXN_, 256, 0, stream>>>(x1, offs, src, wgt, nlist, ncount, x2c);

  // scoring head
  prep_av<<<B_, 256, 0, stream>>>(embed, x2c, markpos, W2, uid, sid, tar_map, a_v, mu, inav, inau);
  seq_inc<<<B_*L_, 256, 0, stream>>>(embed, x2c, markpos, W1, a_v, inav, inau,
                                     node_ids, seq_map, seq_idx, seq_len, uid,
                                     seqs_time, clk_time, tau_p, delta, acc);
  finalize<<<1, 128, 0, stream>>>(mu, acc, out);
}

// Round 4
// 223.851 us; speedup vs baseline: 1.5969x; 1.0820x over previous
//
#include <hip/hip_runtime.h>
#include <hip/hip_bf16.h>
#include <math.h>

// Problem constants (match reference)
#define NT_     64000
#define E_      400000
#define B_      128
#define L_      50
#define KD_     256     // K*D
#define D_      64
#define N_USER_ 100000
#define MAXN_   (B_*L_ + B_)   // 6528 max distinct head nodes

// ---------------- wave helpers ----------------
__device__ __forceinline__ float wred(float v){
#pragma unroll
  for(int s=32;s;s>>=1) v += __shfl_xor(v, s, 64);
  return v;
}
__device__ __forceinline__ int wredi(int v){
#pragma unroll
  for(int s=32;s;s>>=1) v += __shfl_xor(v, s, 64);
  return v;
}

// ---------------- threefry2x32 (JAX key(1) == (0,1)), partitionable XOR-fold ----------------
__device__ __forceinline__ unsigned rotl(unsigned x, int r){ return (x<<r)|(x>>(32-r)); }

__device__ void tf2x32(unsigned c0, unsigned c1, unsigned &o0, unsigned &o1){
  const unsigned k0=0u, k1=1u;
  const unsigned k2=k0^k1^0x1BD11BDAu;
  unsigned x0=c0+k0, x1=c1+k1;
  const int RA[4]={13,15,26,6};
  const int RB[4]={17,29,16,24};
#pragma unroll
  for(int i=0;i<4;i++){ x0+=x1; x1=rotl(x1,RA[i]); x1^=x0; }
  x0+=k1; x1+=k2+1u;
#pragma unroll
  for(int i=0;i<4;i++){ x0+=x1; x1=rotl(x1,RB[i]); x1^=x0; }
  x0+=k2; x1+=k0+2u;
#pragma unroll
  for(int i=0;i<4;i++){ x0+=x1; x1=rotl(x1,RA[i]); x1^=x0; }
  x0+=k0; x1+=k1+3u;
#pragma unroll
  for(int i=0;i<4;i++){ x0+=x1; x1=rotl(x1,RB[i]); x1^=x0; }
  x0+=k1; x1+=k2+4u;
#pragma unroll
  for(int i=0;i<4;i++){ x0+=x1; x1=rotl(x1,RA[i]); x1^=x0; }
  x0+=k2; x1+=k0+5u;
  o0=x0; o1=x1;
}

// Gumbel noise matching jax.random.uniform(key(1),(B,L,K),f32,1e-4,1-1e-4)
__device__ float gumbel_at(int idx){
  unsigned o0,o1;
  tf2x32(0u, (unsigned)idx, o0, o1);      // counts uint64 iota: hi=0, lo=idx
  unsigned bits = o0 ^ o1;                 // 32-bit XOR fold (partitionable)
  unsigned fb = (bits>>9) | 0x3f800000u;   // [1,2)
  float f = __uint_as_float(fb) - 1.0f;    // [0,1)
  const float mn=1e-4f, mx=1.0f-1e-4f;
  float u = fmaxf(mn, f*(mx-mn)+mn);
  return -logf(-logf(u));
}

// ---------------- mark & dedup head nodes (seq_map ∪ tar_map) ----------------
__global__ void mark_assign(const int* __restrict__ seq_map, const int* __restrict__ tar_map,
                            int* __restrict__ markpos, int* __restrict__ nlist,
                            int* __restrict__ ncount, int* __restrict__ need){
  int p = blockIdx.x*256 + threadIdx.x;
  if(p >= MAXN_) return;
  int n = (p < B_*L_) ? seq_map[p] : tar_map[p - B_*L_];
  int old = atomicCAS(&markpos[n], -1, -2);
  if(old == -1){
    int s = atomicAdd(ncount, 1);
    nlist[s] = n;
    need[n] = 1;
    __threadfence();
    markpos[n] = s;
  }
}

// ---------------- x0 staging + degree count (fused) ----------------
__global__ void gather_count(const float4* __restrict__ embed4, const int* __restrict__ node_ids,
                             const int* __restrict__ col, float4* __restrict__ x04,
                             int* __restrict__ cnt){
  int i = blockIdx.x*256 + threadIdx.x;   // over NT_*64 float4s (4.096M >= E_)
  int node = i>>6, q = i&63;
  int nid = node_ids[node];
  x04[i] = embed4[(size_t)nid*64 + q];
  if(i < E_) atomicAdd(&cnt[col[i]], 1);
}

// ---------------- CSR scan ----------------
__global__ void block_sums(const int* __restrict__ cnt, int* __restrict__ bsum){
  int i = blockIdx.x*256 + threadIdx.x;   // NT_ multiple of 256
  int v = wredi(cnt[i]);
  __shared__ int ws[4];
  if((threadIdx.x&63)==0) ws[threadIdx.x>>6]=v;
  __syncthreads();
  if(threadIdx.x==0) bsum[blockIdx.x]=ws[0]+ws[1]+ws[2]+ws[3];
}

__global__ void scan_bsum(int* __restrict__ bsum){
  const int nb = NT_/256;                 // 250
  int i = threadIdx.x;
  int v = (i<nb)? bsum[i] : 0;
  int lane = i&63, wv = i>>6;
  int s = v;
#pragma unroll
  for(int d=1; d<64; d<<=1){ int t = __shfl_up(s, d, 64); if(lane>=d) s += t; }
  __shared__ int ws[4];
  if(lane==63) ws[wv]=s;
  __syncthreads();
  int add=0;
  for(int w=0;w<wv;w++) add += ws[w];
  if(i<nb) bsum[i] = add + s - v;         // exclusive scan of block sums
}

// offs + cur (mutable copy for slot assignment) + dinv, one pass
__global__ void scan_final(const int* __restrict__ cnt, const int* __restrict__ bsumx,
                           int* __restrict__ offs, int* __restrict__ cur,
                           float* __restrict__ dinv){
  int i = blockIdx.x*256 + threadIdx.x;
  int v = cnt[i];
  int lane = threadIdx.x&63, wv = threadIdx.x>>6;
  int s = v;
#pragma unroll
  for(int d=1; d<64; d<<=1){ int t = __shfl_up(s, d, 64); if(lane>=d) s += t; }
  __shared__ int ws[4];
  if(lane==63) ws[wv]=s;
  __syncthreads();
  int add = bsumx[blockIdx.x];
  for(int w=0;w<wv;w++) add += ws[w];
  int off0 = add + s - v;
  offs[i] = off0;
  cur[i]  = off0;
  dinv[i] = (v>0)? (1.0f/sqrtf((float)v)) : 0.0f;
  if(i == NT_-1) offs[NT_] = add + s;     // = E_
}

// per-slot (src_row, weight = dinv[r]*dinv[c]*0.25); propagate need to head in-neighbors
__global__ void fill_csr(const int* __restrict__ row, const int* __restrict__ col,
                         const float* __restrict__ dinv, const int* __restrict__ markpos,
                         int* __restrict__ cur, int* __restrict__ src, float* __restrict__ wgt,
                         int* __restrict__ need){
  int e = blockIdx.x*256 + threadIdx.x;
  if(e<E_){
    int c = col[e], r = row[e];
    int slot = atomicAdd(&cur[c], 1);
    src[slot] = r;
    wgt[slot] = dinv[r]*dinv[c]*0.25f;
    if(markpos[c] != -1) need[r] = 1;     // x1[r] will be read by conv2
  }
}

// ---------------- conv1 (filtered): wave-per-node, float4 per lane, 4-edge unroll ----------------
__global__ void aggregate1(const float4* __restrict__ x04, const int* __restrict__ offs,
                           const int* __restrict__ src, const float* __restrict__ wgt,
                           const int* __restrict__ need, float4* __restrict__ x14){
  int wv = threadIdx.x>>6, lane = threadIdx.x&63;
  int c = blockIdx.x*4 + wv;
  if(!need[c]) return;                    // x1[c] never read downstream
  float4 acc = {0.f,0.f,0.f,0.f};
  int s = offs[c], e = offs[c+1];
  int i = s;
  for(; i+4<=e; i+=4){
    int   s0=src[i],   s1=src[i+1], s2=src[i+2], s3=src[i+3];
    float w0=wgt[i],   w1=wgt[i+1], w2=wgt[i+2], w3=wgt[i+3];
    float4 v0=x04[(size_t)s0*64+lane];
    float4 v1=x04[(size_t)s1*64+lane];
    float4 v2=x04[(size_t)s2*64+lane];
    float4 v3=x04[(size_t)s3*64+lane];
    acc.x = fmaf(v0.x,w0,fmaf(v1.x,w1,fmaf(v2.x,w2,fmaf(v3.x,w3,acc.x))));
    acc.y = fmaf(v0.y,w0,fmaf(v1.y,w1,fmaf(v2.y,w2,fmaf(v3.y,w3,acc.y))));
    acc.z = fmaf(v0.z,w0,fmaf(v1.z,w1,fmaf(v2.z,w2,fmaf(v3.z,w3,acc.z))));
    acc.w = fmaf(v0.w,w0,fmaf(v1.w,w1,fmaf(v2.w,w2,fmaf(v3.w,w3,acc.w))));
  }
  for(; i<e; i++){
    int s0=src[i]; float w0=wgt[i];
    float4 v0=x04[(size_t)s0*64+lane];
    acc.x=fmaf(v0.x,w0,acc.x); acc.y=fmaf(v0.y,w0,acc.y);
    acc.z=fmaf(v0.z,w0,acc.z); acc.w=fmaf(v0.w,w0,acc.w);
  }
  x14[(size_t)c*64+lane] = acc;
}

// ---------------- conv2 fused (only head nodes): z -> softmax -> aggregate ----------------
__global__ void conv2_fused(const float* __restrict__ x1, const int* __restrict__ offs,
                            const int* __restrict__ src, const float* __restrict__ wgt,
                            const int* __restrict__ nlist, const int* __restrict__ ncount,
                            float* __restrict__ x2c){
  int slot = blockIdx.x;
  if(slot >= *ncount) return;
  int c = nlist[slot];
  int t = threadIdx.x, k = t>>6, lane = t&63;
  float tx = tanhf(x1[(size_t)c*KD_ + t]);
  float acc = 0.f;
  __shared__ float zs[4];
  int s = offs[c], e = offs[c+1];
  for(int i=s;i<e;i++){
    int r = src[i];
    float xr = x1[(size_t)r*KD_ + t];
    float zk = wred(xr*tx);               // z[e,k] = dot(x1[row,k,:], tanh(x1[col,k,:]))
    if(lane==0) zs[k] = zk;
    __syncthreads();
    float z0=zs[0], z1=zs[1], z2=zs[2], z3=zs[3];
    // softmax(1+z) over k == softmax(z) (shift-invariant)
    float m = fmaxf(fmaxf(z0,z1), fmaxf(z2,z3));
    float e0=expf(z0-m), e1=expf(z1-m), e2=expf(z2-m), e3=expf(z3-m);
    float inv = (4.f*wgt[i])/(e0+e1+e2+e3);   // base = 4*wgt
    float w = ((k==0)?e0:(k==1)?e1:(k==2)?e2:e3) * inv;
    acc = fmaf(xr, w, acc);
    __syncthreads();
  }
  x2c[(size_t)slot*KD_ + t] = acc;
}

// ---------------- head (prep_av folded into per-(b,l) block) ----------------
__global__ void head_fused(const float* __restrict__ embed, const float* __restrict__ x2c,
                           const int* __restrict__ markpos,
                           const float* __restrict__ W1, const float* __restrict__ W2,
                           const int* __restrict__ node_ids, const int* __restrict__ seq_map,
                           const int* __restrict__ tar_map, const int* __restrict__ seq_idx,
                           const int* __restrict__ seq_len,
                           const int* __restrict__ uid, const int* __restrict__ sid,
                           const float* __restrict__ seqs_time, const float* __restrict__ clk_time,
                           const float* __restrict__ tau_p, const float* __restrict__ delta,
                           float* __restrict__ mu, float* __restrict__ acc){
  int bl = blockIdx.x;
  int b = bl / L_, l = bl % L_;
  if(l >= seq_len[b]) return;           // masked position contributes exactly 0
  int t = threadIdx.x, k = t>>6, lane = t&63;
  // a_v = x2[tar] @ W2^T + embed[sid+N_USER]   (recomputed per block; 64 shfl-FMAs)
  float xt = x2c[(size_t)markpos[tar_map[b]]*KD_ + t];
  float av = embed[((size_t)(N_USER_ + sid[b]))*KD_ + t];
  const float* w2row = W2 + lane*64;
#pragma unroll 8
  for(int d=0; d<64; d++) av = fmaf(__shfl(xt, d, 64), w2row[d], av);
  float au = embed[(size_t)uid[b]*KD_ + t];
  // seq_embed = x2[n] @ W1^T + embed[node_ids[n]]
  int n = seq_map[bl];
  float xv = x2c[(size_t)markpos[n]*KD_ + t];
  float se = embed[(size_t)node_ids[n]*KD_ + t];
  const float* w1row = W1 + lane*64;
#pragma unroll 8
  for(int d=0; d<64; d++) se = fmaf(__shfl(xv, d, 64), w1row[d], se);
  float nv  = wred(av*av);
  float nu  = wred(au*au);
  float duv = wred(av*au);
  float dv  = wred(se*av);
  float du  = wred(se*au);
  float ns  = wred(se*se);
  __shared__ float s6[6][4];
  if(lane==0){ s6[0][k]=nv; s6[1][k]=nu; s6[2][k]=duv; s6[3][k]=dv; s6[4][k]=du; s6[5][k]=ns; }
  __syncthreads();
  if(t==0){
    float jv  = expf(-(clk_time[b]-seqs_time[bl]) * (1.0f/1000.0f) * delta[uid[b]]);
    float tau = tau_p[seq_idx[bl]];
    float gam[4], lg[4];
    float m = -1e30f;
#pragma unroll
    for(int kk=0;kk<4;kk++){
      float rnv = fmaxf(sqrtf(s6[0][kk]), 1e-8f);
      float rnu = fmaxf(sqrtf(s6[1][kk]), 1e-8f);
      float ins = 1.f/fmaxf(sqrtf(s6[5][kk]), 1e-8f);
      if(l==0) mu[b*4+kk] = s6[2][kk]/(rnv*rnu);
      gam[kk] = s6[3][kk]*ins/rnv;
      float logit = s6[4][kk]*ins/rnu;
      lg[kk] = (logit + gumbel_at(bl*4+kk))/tau;
      m = fmaxf(m, lg[kk]);
    }
    float es[4], ssum=0.f;
#pragma unroll
    for(int kk=0;kk<4;kk++){ es[kk]=expf(lg[kk]-m); ssum+=es[kk]; }
    float isum = 1.f/ssum;
#pragma unroll
    for(int kk=0;kk<4;kk++)
      atomicAdd(&acc[b*4+kk], jv * gam[kk] * es[kk]*isum);
  }
}

__global__ void finalize(const float* __restrict__ mu, const float* __restrict__ acc,
                         float* __restrict__ out){
  int b = threadIdx.x;
  if(b < B_){
    float s = 0.f;
#pragma unroll
    for(int k=0;k<4;k++) s += mu[b*4+k] + acc[b*4+k];
    out[b] = s * 0.25f;
  }
}

// ---------------- launch ----------------
extern "C" void kernel_launch(void* const* d_in, const int* in_sizes, int n_in,
                              void* d_out, int out_size, void* d_ws, size_t ws_size,
                              hipStream_t stream){
  const float* embed = (const float*)d_in[0];
  const float* delta = (const float*)d_in[1];
  const float* tau_p = (const float*)d_in[2];
  const float* W1    = (const float*)d_in[3];
  const float* W2    = (const float*)d_in[4];
  const float* seqs_time = (const float*)d_in[5];
  const float* clk_time  = (const float*)d_in[6];
  const int* uid      = (const int*)d_in[7];
  const int* sid      = (const int*)d_in[8];
  const int* node_ids = (const int*)d_in[9];
  const int* edge_index = (const int*)d_in[10];
  const int* seq_map  = (const int*)d_in[11];
  const int* tar_map  = (const int*)d_in[12];
  const int* seq_idx  = (const int*)d_in[13];
  const int* seq_len  = (const int*)d_in[14];
  const int* row = edge_index;
  const int* col = edge_index + E_;
  float* out = (float*)d_out;

  // carve: zero-init region first (acc..ncount..cnt..need contiguous -> ONE memset)
  char* wp = (char*)d_ws;
  size_t o = 0;
  auto carve = [&](size_t bytes)->char*{ char* r = wp + o; o = (o + bytes + 255) & ~(size_t)255; return r; };
  float* acc    = (float*)carve((size_t)B_*4*4);
  int*   ncount = (int*)  carve((size_t)4);
  int*   cnt    = (int*)  carve((size_t)NT_*4);
  int*   need   = (int*)  carve((size_t)NT_*4);
  char*  zero_end = wp + o;
  int*   markpos= (int*)  carve((size_t)NT_*4);
  float* mu     = (float*)carve((size_t)B_*4*4);
  int*   bsum   = (int*)  carve((size_t)256*4);
  int*   nlist  = (int*)  carve((size_t)MAXN_*4);
  float* dinv   = (float*)carve((size_t)NT_*4);
  int*   cur    = (int*)  carve((size_t)NT_*4);
  int*   offs   = (int*)  carve((size_t)(NT_+1)*4);
  int*   src    = (int*)  carve((size_t)E_*4);
  float* wgt    = (float*)carve((size_t)E_*4);
  float* x2c    = (float*)carve((size_t)MAXN_*KD_*4);
  float* x0     = (float*)carve((size_t)NT_*KD_*4);   // 64 MB
  float* x1     = (float*)carve((size_t)NT_*KD_*4);   // 64 MB

  hipMemsetAsync(acc, 0, (size_t)(zero_end - (char*)acc), stream);   // acc,ncount,cnt,need
  hipMemsetAsync(markpos, 0xFF, (size_t)NT_*4, stream);              // -1

  // head-node dedup (independent of CSR; must precede fill_csr's need-propagation)
  mark_assign<<<(MAXN_+255)/256, 256, 0, stream>>>(seq_map, tar_map, markpos, nlist, ncount, need);

  // x0 = embed[node_ids] + degree count, fused
  gather_count<<<NT_*64/256, 256, 0, stream>>>((const float4*)embed, node_ids, col,
                                               (float4*)x0, cnt);

  // CSR by col (offs/cur/dinv in one pass; slot = atomicAdd(cur))
  block_sums<<<NT_/256, 256, 0, stream>>>(cnt, bsum);
  scan_bsum<<<1, 256, 0, stream>>>(bsum);
  scan_final<<<NT_/256, 256, 0, stream>>>(cnt, bsum, offs, cur, dinv);
  fill_csr<<<(E_+255)/256, 256, 0, stream>>>(row, col, dinv, markpos, cur, src, wgt, need);

  // conv1, only for nodes whose x1 is read downstream (head ∪ in-neighbors of head)
  aggregate1<<<NT_/4, 256, 0, stream>>>((const float4*)x0, offs, src, wgt, need, (float4*)x1);

  // conv2 only for head nodes (seq_map ∪ tar_map)
  conv2_fused<<<MAXN_, 256, 0, stream>>>(x1, offs, src, wgt, nlist, ncount, x2c);

  // scoring head (a_v recomputed per block; mu written by l==0 blocks)
  head_fused<<<B_*L_, 256, 0, stream>>>(embed, x2c, markpos, W1, W2,
                                        node_ids, seq_map, tar_map, seq_idx, seq_len,
                                        uid, sid, seqs_time, clk_time, tau_p, delta,
                                        mu, acc);
  finalize<<<1, 128, 0, stream>>>(mu, acc, out);
}